// Round 7
// baseline (378.108 us; speedup 1.0000x reference)
//
#include <hip/hip_runtime.h>
#include <cmath>

#define NEG_SLOPE 0.2f
static constexpr int NGRAPH = 64;

__device__ __forceinline__ float lrelu(float x) {
  return x > 0.f ? x : NEG_SLOPE * x;
}

// ---- layer-0 transform: h[n,c] = x[n] * W0[c] (Fin = 1), plus head dots ----
__global__ void transform0_kernel(const float* __restrict__ x,
                                  const float* __restrict__ W0,
                                  const float* __restrict__ a_src,
                                  const float* __restrict__ a_dst,
                                  float* __restrict__ h,
                                  float* __restrict__ as_,
                                  float* __restrict__ ad_,
                                  int n_nodes) {
  int lane = threadIdx.x & 63;
  int wave = (blockIdx.x * blockDim.x + threadIdx.x) >> 6;
  int nwaves = (gridDim.x * blockDim.x) >> 6;
  int head = lane >> 4, ch = lane & 15;
  float w0 = W0[lane];
  float asc = a_src[head * 16 + ch];
  float adc = a_dst[head * 16 + ch];
  for (int n = wave; n < n_nodes; n += nwaves) {
    float v = x[n] * w0;
    h[(size_t)n * 64 + lane] = v;
    float s = v * asc, d = v * adc;
#pragma unroll
    for (int off = 8; off; off >>= 1) {
      s += __shfl_down(s, off, 16);
      d += __shfl_down(d, off, 16);
    }
    if (ch == 0) { as_[n * 4 + head] = s; ad_[n * 4 + head] = d; }
  }
}

// ---- hidden-layer transform: W column in 64 VGPRs; h-row via s_load ----
__global__ void transform_kernel(const float* __restrict__ hin,
                                 const float* __restrict__ W,
                                 const float* __restrict__ a_src,
                                 const float* __restrict__ a_dst,
                                 float* __restrict__ hout,
                                 float* __restrict__ as_,
                                 float* __restrict__ ad_,
                                 int n_nodes) {
  int lane = threadIdx.x & 63;
  int wave = (blockIdx.x * blockDim.x + threadIdx.x) >> 6;
  int nwaves = (gridDim.x * blockDim.x) >> 6;
  int head = lane >> 4, ch = lane & 15;
  float wreg[64];
#pragma unroll
  for (int k = 0; k < 64; ++k) wreg[k] = W[k * 64 + lane];
  float asc = a_src[head * 16 + ch];
  float adc = a_dst[head * 16 + ch];
  for (int n = wave; n < n_nodes; n += nwaves) {
    int nu = __builtin_amdgcn_readfirstlane(n);
    const float* hrow = hin + (size_t)nu * 64;
    float acc = 0.f;
#pragma unroll
    for (int k = 0; k < 64; ++k) acc = fmaf(hrow[k], wreg[k], acc);
    hout[(size_t)nu * 64 + lane] = acc;
    float s = acc * asc, d = acc * adc;
#pragma unroll
    for (int off = 8; off; off >>= 1) {
      s += __shfl_down(s, off, 16);
      d += __shfl_down(d, off, 16);
    }
    if (ch == 0) { as_[nu * 4 + head] = s; ad_[nu * 4 + head] = d; }
  }
}

// ================= binned CSR build (nodes-per-bucket = 256) ================

__global__ void bucket_hist_kernel(const int* __restrict__ dst,
                                   int* __restrict__ bucketCounts,
                                   int nedge, int nb, int tile) {
  __shared__ int hist[256];
  hist[threadIdx.x] = 0;
  __syncthreads();
  int start = blockIdx.x * tile;
  int end = min(start + tile, nedge);
  for (int e = start + threadIdx.x; e < end; e += 256)
    atomicAdd(&hist[dst[e] >> 8], 1);
  __syncthreads();
  if (threadIdx.x < nb && hist[threadIdx.x])
    atomicAdd(&bucketCounts[threadIdx.x], hist[threadIdx.x]);
}

__global__ void bucket_scan_kernel(const int* __restrict__ bucketCounts,
                                   int* __restrict__ bucketOffsets,
                                   int* __restrict__ bucketCursor, int nb) {
  __shared__ int tmp[256];
  int tid = threadIdx.x;
  int v = (tid < nb) ? bucketCounts[tid] : 0;
  tmp[tid] = v;
  __syncthreads();
#pragma unroll
  for (int off = 1; off < 256; off <<= 1) {
    int t = (tid >= off) ? tmp[tid - off] : 0;
    __syncthreads();
    tmp[tid] += t;
    __syncthreads();
  }
  if (tid < nb) {
    int excl = tmp[tid] - v;
    bucketOffsets[tid] = excl;
    bucketCursor[tid] = excl;
  }
  if (tid == 0) bucketOffsets[nb] = tmp[255];
}

__global__ void bucket_scatter_kernel(const int* __restrict__ src,
                                      const int* __restrict__ dst,
                                      int* __restrict__ bucketCursor,
                                      int2* __restrict__ binEdges,
                                      int nedge, int nb, int tile) {
  __shared__ int hist[256];
  __shared__ int base[256];
  hist[threadIdx.x] = 0;
  __syncthreads();
  int start = blockIdx.x * tile;
  int end = min(start + tile, nedge);
  for (int e = start + threadIdx.x; e < end; e += 256)
    atomicAdd(&hist[dst[e] >> 8], 1);
  __syncthreads();
  if (threadIdx.x < nb) {
    int c = hist[threadIdx.x];
    base[threadIdx.x] = c ? atomicAdd(&bucketCursor[threadIdx.x], c) : 0;
    hist[threadIdx.x] = 0;
  }
  __syncthreads();
  for (int e = start + threadIdx.x; e < end; e += 256) {
    int b = dst[e] >> 8;
    int r = atomicAdd(&hist[b], 1);
    binEdges[base[b] + r] = make_int2(src[e], dst[e]);
  }
}

__global__ void csr_build_kernel(const int2* __restrict__ binEdges,
                                 const int* __restrict__ bucketOffsets,
                                 int2* __restrict__ rowinfo,
                                 int* __restrict__ csr, int n_nodes) {
  __shared__ int hist[256];
  __shared__ int tmp[256];
  int tid = threadIdx.x;
  int b = blockIdx.x;
  int n0 = b << 8;
  int nLoc = min(256, n_nodes - n0);
  int eBase = bucketOffsets[b];
  int cntE = bucketOffsets[b + 1] - eBase;
  hist[tid] = 0;
  __syncthreads();
  for (int i = tid; i < cntE; i += 256)
    atomicAdd(&hist[binEdges[eBase + i].y - n0], 1);
  __syncthreads();
  int v = (tid < nLoc) ? hist[tid] + 1 : 0;  // +1 = self-loop
  tmp[tid] = v;
  __syncthreads();
#pragma unroll
  for (int off = 1; off < 256; off <<= 1) {
    int t = (tid >= off) ? tmp[tid - off] : 0;
    __syncthreads();
    tmp[tid] += t;
    __syncthreads();
  }
  int excl = tmp[tid] - v;
  __syncthreads();
  if (tid < nLoc) {
    int rowStart = eBase + n0 + excl;
    rowinfo[n0 + tid] = make_int2(rowStart, v);
    csr[rowStart] = n0 + tid;  // self edge in slot 0
    hist[tid] = excl + 1;      // local cursor
  }
  __syncthreads();
  for (int i = tid; i < cntE; i += 256) {
    int2 e = binEdges[eBase + i];
    int l = e.y - n0;
    int r = atomicAdd(&hist[l], 1);
    csr[eBase + n0 + r] = e.x;
  }
}

// ========== fused softmax + weighted gather, wave-per-node ==================
// Fast path (deg<=64): no max-subtraction (cancels exactly; e bounded).
// Gather software-pipelined 8-deep: 8 dwordx4 gathers issued back-to-back
// (predicated weight, idx 0 for inactive — wasted gathers measured ~free),
// then consumed. Doubles loads-in-flight per wave vs the 4-chunk version.
__global__ void aggregate_kernel(const int2* __restrict__ rowinfo,
                                 const int* __restrict__ csr,
                                 const float* __restrict__ as_,
                                 const float* __restrict__ ad_,
                                 const float* __restrict__ h,
                                 const float* __restrict__ bias,
                                 float* __restrict__ hout, int n_nodes) {
  __shared__ int lds_s[4][64];
  __shared__ float lds_w[4][4 * 68];  // stride 68: conflict-free
  int lane = threadIdx.x & 63;
  int wv = threadIdx.x >> 6;
  int node = (blockIdx.x * blockDim.x + threadIdx.x) >> 6;
  if (node >= n_nodes) return;
  node = __builtin_amdgcn_readfirstlane(node);  // force scalar loads below
  int2 ri = rowinfo[node];
  int row = ri.x;
  int deg = ri.y;
  const float4 ad4 = *(const float4*)(ad_ + node * 4);

  if (deg <= 64) {
    bool valid = lane < deg;
    int s = 0;
    float w0 = 0.f, w1 = 0.f, w2 = 0.f, w3 = 0.f;
    if (valid) {
      s = csr[row + lane];
      const float4 a4 = *(const float4*)(as_ + s * 4);
      w0 = __expf(lrelu(a4.x + ad4.x));
      w1 = __expf(lrelu(a4.y + ad4.y));
      w2 = __expf(lrelu(a4.z + ad4.z));
      w3 = __expf(lrelu(a4.w + ad4.w));
    }
    lds_s[wv][lane] = s;
    lds_w[wv][0 * 68 + lane] = w0;
    lds_w[wv][1 * 68 + lane] = w1;
    lds_w[wv][2 * 68 + lane] = w2;
    lds_w[wv][3 * 68 + lane] = w3;
    // lanes re-split 16x4: 16-lane group g handles edge j = it*4+g, 4 ch/lane
    int grp = lane >> 4;
    int chBase = (lane & 15) * 4;
    int headL = (lane & 15) >> 2;
    const int* sp = &lds_s[wv][0];
    const float* wp = &lds_w[wv][headL * 68];
    float ax = 0.f, ay = 0.f, az = 0.f, aw = 0.f, zacc = 0.f;
    int iters = (deg + 3) >> 2;  // 1..16, wave-uniform
    for (int base = 0; base < iters; base += 8) {
      float4 g[8];
      float u[8];
#pragma unroll
      for (int k = 0; k < 8; ++k) {
        int it = base + k;
        int j = (it * 4 + grp) & 63;
        int sj = sp[j];
        u[k] = (it < iters) ? wp[j] : 0.f;
        g[k] = *(const float4*)(h + (size_t)sj * 64 + chBase);
      }
#pragma unroll
      for (int k = 0; k < 8; ++k) {
        ax = fmaf(u[k], g[k].x, ax);
        ay = fmaf(u[k], g[k].y, ay);
        az = fmaf(u[k], g[k].z, az);
        aw = fmaf(u[k], g[k].w, aw);
        zacc += u[k];
      }
    }
    // combine the 4 edge-groups (lanes L, L^16, L^32, L^48)
    ax += __shfl_xor(ax, 16); ax += __shfl_xor(ax, 32);
    ay += __shfl_xor(ay, 16); ay += __shfl_xor(ay, 32);
    az += __shfl_xor(az, 16); az += __shfl_xor(az, 32);
    aw += __shfl_xor(aw, 16); aw += __shfl_xor(aw, 32);
    zacc += __shfl_xor(zacc, 16); zacc += __shfl_xor(zacc, 32);
    if (lane < 16) {
      const float4 b4 = *(const float4*)(bias + chBase);
      float4 o;
      o.x = ax / zacc + b4.x;
      o.y = ay / zacc + b4.y;
      o.z = az / zacc + b4.z;
      o.w = aw / zacc + b4.w;
      *(float4*)(hout + (size_t)node * 64 + chBase) = o;
    }
    return;
  }

  // --- slow path (deg > 64): two-pass with max, scalar gather (rare) ---
  int head = lane >> 4;
  float m0 = -INFINITY, m1 = -INFINITY, m2 = -INFINITY, m3 = -INFINITY;
  for (int base = 0; base < deg; base += 64) {
    int idx = base + lane;
    if (idx < deg) {
      int s = csr[row + idx];
      const float4 a4 = *(const float4*)(as_ + s * 4);
      m0 = fmaxf(m0, lrelu(a4.x + ad4.x));
      m1 = fmaxf(m1, lrelu(a4.y + ad4.y));
      m2 = fmaxf(m2, lrelu(a4.z + ad4.z));
      m3 = fmaxf(m3, lrelu(a4.w + ad4.w));
    }
  }
#pragma unroll
  for (int off = 32; off; off >>= 1) {
    m0 = fmaxf(m0, __shfl_xor(m0, off));
    m1 = fmaxf(m1, __shfl_xor(m1, off));
    m2 = fmaxf(m2, __shfl_xor(m2, off));
    m3 = fmaxf(m3, __shfl_xor(m3, off));
  }
  float z0 = 0.f, z1 = 0.f, z2 = 0.f, z3 = 0.f;
  float acc = 0.f;
  for (int base = 0; base < deg; base += 64) {
    int idx = base + lane;
    int s = 0;
    float w0 = 0.f, w1 = 0.f, w2 = 0.f, w3 = 0.f;
    if (idx < deg) {
      s = csr[row + idx];
      const float4 a4 = *(const float4*)(as_ + s * 4);
      w0 = __expf(lrelu(a4.x + ad4.x) - m0);
      w1 = __expf(lrelu(a4.y + ad4.y) - m1);
      w2 = __expf(lrelu(a4.z + ad4.z) - m2);
      w3 = __expf(lrelu(a4.w + ad4.w) - m3);
    }
    z0 += w0; z1 += w1; z2 += w2; z3 += w3;
    lds_s[wv][lane] = s;
    lds_w[wv][0 * 68 + lane] = w0;
    lds_w[wv][1 * 68 + lane] = w1;
    lds_w[wv][2 * 68 + lane] = w2;
    lds_w[wv][3 * 68 + lane] = w3;
    int cnt = min(64, deg - base);
    for (int j = 0; j < cnt; ++j) {
      int sj = lds_s[wv][j];
      float wj = lds_w[wv][head * 68 + j];
      acc = fmaf(wj, h[(size_t)sj * 64 + lane], acc);
    }
  }
#pragma unroll
  for (int off = 32; off; off >>= 1) {
    z0 += __shfl_xor(z0, off);
    z1 += __shfl_xor(z1, off);
    z2 += __shfl_xor(z2, off);
    z3 += __shfl_xor(z3, off);
  }
  float zsel = head == 0 ? z0 : head == 1 ? z1 : head == 2 ? z2 : z3;
  hout[(size_t)node * 64 + lane] = acc / zsel + bias[lane];
}

// ============== fused mean-pool + final linear: one block per graph =========
__global__ void pool_final_kernel(const float* __restrict__ h,
                                  const int* __restrict__ batch,
                                  const float* __restrict__ Wf,
                                  const float* __restrict__ bf,
                                  float* __restrict__ out, int n_nodes) {
  __shared__ float rowsum[4][64];
  int g = blockIdx.x;
  int tid = threadIdx.x;
  // segment bounds via binary search in sorted batch (all threads redundant)
  int lo = 0, hi = n_nodes;
  while (lo < hi) { int mid = (lo + hi) >> 1; if (batch[mid] < g) lo = mid + 1; else hi = mid; }
  int start = lo;
  lo = 0; hi = n_nodes;
  while (lo < hi) { int mid = (lo + hi) >> 1; if (batch[mid] < g + 1) lo = mid + 1; else hi = mid; }
  int end = lo;
  int col = tid & 63, rowgrp = tid >> 6;
  float acc = 0.f;
  for (int n = start + rowgrp; n < end; n += 4)
    acc += h[(size_t)n * 64 + col];
  rowsum[rowgrp][col] = acc;
  __syncthreads();
  if (tid < 64) {
    float s = rowsum[0][tid] + rowsum[1][tid] + rowsum[2][tid] + rowsum[3][tid];
    float cg = (float)(end - start);
    cg = cg > 1.f ? cg : 1.f;
    rowsum[0][tid] = s / cg;
  }
  __syncthreads();
  if (tid < 5) {
    float a = bf[tid];
    for (int c = 0; c < 64; ++c)
      a += rowsum[0][c] * Wf[c * 5 + tid];
    out[g * 5 + tid] = a;
  }
}

extern "C" void kernel_launch(void* const* d_in, const int* in_sizes, int n_in,
                              void* d_out, int out_size, void* d_ws, size_t ws_size,
                              hipStream_t stream) {
  const float* x     = (const float*)d_in[0];
  const int*   ei    = (const int*)d_in[1];
  const int*   batch = (const int*)d_in[2];
  const float* W0    = (const float*)d_in[3];
  const float* as0   = (const float*)d_in[4];
  const float* ad0   = (const float*)d_in[5];
  const float* b0    = (const float*)d_in[6];
  const float* Wh    = (const float*)d_in[7];
  const float* ash   = (const float*)d_in[8];
  const float* adh   = (const float*)d_in[9];
  const float* bh    = (const float*)d_in[10];
  const float* Wf    = (const float*)d_in[11];
  const float* bf    = (const float*)d_in[12];
  float* out = (float*)d_out;

  const int N = in_sizes[0];       // 50000
  const int E = in_sizes[1] / 2;   // 800000
  const int* src = ei;
  const int* dst = ei + E;
  const int nE = E + N;
  const int NB = (N + 255) >> 8;   // buckets of 256 nodes (196)

  // workspace layout
  float* ws  = (float*)d_ws;
  float* hA  = ws;                              // N*64
  float* hB  = hA + (size_t)N * 64;             // N*64
  float* asb = hB + (size_t)N * 64;             // N*4
  float* adb = asb + (size_t)N * 4;             // N*4
  int2* rowinfo = (int2*)(adb + (size_t)N * 4); // N int2
  int* csr     = (int*)(rowinfo + N);           // nE
  int2* binEdges = (int2*)(csr + nE);           // E int2
  int* bucketCounts  = (int*)(binEdges + E);    // NB+1
  int* bucketOffsets = bucketCounts + NB + 1;   // NB+1
  int* bucketCursor  = bucketOffsets + NB + 1;  // NB

  const int TILE = 2048;
  const int binBlocks = (E + TILE - 1) / TILE;
  const int nodeWaveBlocks = (N + 3) / 4;

  // ---- CSR build inputs zeroed via async memset (capture-legal) ----
  hipMemsetAsync(bucketCounts, 0, (size_t)(NB + 1) * sizeof(int), stream);
  transform0_kernel<<<2048, 256, 0, stream>>>(x, W0, as0, ad0, hA, asb, adb, N);
  bucket_hist_kernel<<<binBlocks, 256, 0, stream>>>(dst, bucketCounts, E, NB, TILE);
  bucket_scan_kernel<<<1, 256, 0, stream>>>(bucketCounts, bucketOffsets, bucketCursor, NB);
  bucket_scatter_kernel<<<binBlocks, 256, 0, stream>>>(src, dst, bucketCursor, binEdges, E, NB, TILE);
  csr_build_kernel<<<NB, 256, 0, stream>>>(binEdges, bucketOffsets, rowinfo, csr, N);

  for (int layer = 0; layer < 4; ++layer) {
    if (layer > 0) {
      transform_kernel<<<2048, 256, 0, stream>>>(hB, Wh + (size_t)(layer - 1) * 64 * 64,
                                                 ash + (layer - 1) * 64, adh + (layer - 1) * 64,
                                                 hA, asb, adb, N);
    }
    const float* bias = (layer == 0) ? b0 : (bh + (layer - 1) * 64);
    aggregate_kernel<<<nodeWaveBlocks, 256, 0, stream>>>(rowinfo, csr,
                                                         asb, adb, hA, bias, hB, N);
  }

  pool_final_kernel<<<NGRAPH, 256, 0, stream>>>(hB, batch, Wf, bf, out, N);
}

// Round 8
// 345.687 us; speedup vs baseline: 1.0938x; 1.0938x over previous
//
#include <hip/hip_runtime.h>
#include <cmath>

#define NEG_SLOPE 0.2f
static constexpr int NGRAPH = 64;

__device__ __forceinline__ float lrelu(float x) {
  return x > 0.f ? x : NEG_SLOPE * x;
}

// ---- fused: [blocks 0..histBlocks) edge-bucket histogram |
//             [histBlocks..) layer-0 transform (Fin = 1) + head dots ----
__global__ void t0_hist_kernel(const float* __restrict__ x,
                               const float* __restrict__ W0,
                               const float* __restrict__ a_src,
                               const float* __restrict__ a_dst,
                               float* __restrict__ h,
                               float* __restrict__ as_,
                               float* __restrict__ ad_,
                               int n_nodes,
                               const int* __restrict__ dst,
                               int* __restrict__ bucketCounts,
                               int nedge, int nb, int tile, int histBlocks) {
  if (blockIdx.x < (unsigned)histBlocks) {
    __shared__ int hist[256];
    hist[threadIdx.x] = 0;
    __syncthreads();
    int start = blockIdx.x * tile;
    int end = min(start + tile, nedge);
    for (int e = start + threadIdx.x; e < end; e += 256)
      atomicAdd(&hist[dst[e] >> 8], 1);
    __syncthreads();
    if (threadIdx.x < nb && hist[threadIdx.x])
      atomicAdd(&bucketCounts[threadIdx.x], hist[threadIdx.x]);
    return;
  }
  int bid = blockIdx.x - histBlocks;
  int lane = threadIdx.x & 63;
  int wave = (bid * blockDim.x + threadIdx.x) >> 6;
  int nwaves = ((gridDim.x - histBlocks) * blockDim.x) >> 6;
  int head = lane >> 4, ch = lane & 15;
  float w0 = W0[lane];
  float asc = a_src[head * 16 + ch];
  float adc = a_dst[head * 16 + ch];
  for (int n = wave; n < n_nodes; n += nwaves) {
    float v = x[n] * w0;
    h[(size_t)n * 64 + lane] = v;
    float s = v * asc, d = v * adc;
#pragma unroll
    for (int off = 8; off; off >>= 1) {
      s += __shfl_down(s, off, 16);
      d += __shfl_down(d, off, 16);
    }
    if (ch == 0) { as_[n * 4 + head] = s; ad_[n * 4 + head] = d; }
  }
}

// ---- hidden-layer transform: W column in 64 VGPRs; h-row via s_load ----
__global__ void transform_kernel(const float* __restrict__ hin,
                                 const float* __restrict__ W,
                                 const float* __restrict__ a_src,
                                 const float* __restrict__ a_dst,
                                 float* __restrict__ hout,
                                 float* __restrict__ as_,
                                 float* __restrict__ ad_,
                                 int n_nodes) {
  int lane = threadIdx.x & 63;
  int wave = (blockIdx.x * blockDim.x + threadIdx.x) >> 6;
  int nwaves = (gridDim.x * blockDim.x) >> 6;
  int head = lane >> 4, ch = lane & 15;
  float wreg[64];
#pragma unroll
  for (int k = 0; k < 64; ++k) wreg[k] = W[k * 64 + lane];
  float asc = a_src[head * 16 + ch];
  float adc = a_dst[head * 16 + ch];
  for (int n = wave; n < n_nodes; n += nwaves) {
    int nu = __builtin_amdgcn_readfirstlane(n);
    const float* hrow = hin + (size_t)nu * 64;
    float acc = 0.f;
#pragma unroll
    for (int k = 0; k < 64; ++k) acc = fmaf(hrow[k], wreg[k], acc);
    hout[(size_t)nu * 64 + lane] = acc;
    float s = acc * asc, d = acc * adc;
#pragma unroll
    for (int off = 8; off; off >>= 1) {
      s += __shfl_down(s, off, 16);
      d += __shfl_down(d, off, 16);
    }
    if (ch == 0) { as_[nu * 4 + head] = s; ad_[nu * 4 + head] = d; }
  }
}

// ================= binned CSR build (nodes-per-bucket = 256) ================

__global__ void bucket_scan_kernel(const int* __restrict__ bucketCounts,
                                   int* __restrict__ bucketOffsets,
                                   int* __restrict__ bucketCursor, int nb) {
  __shared__ int tmp[256];
  int tid = threadIdx.x;
  int v = (tid < nb) ? bucketCounts[tid] : 0;
  tmp[tid] = v;
  __syncthreads();
#pragma unroll
  for (int off = 1; off < 256; off <<= 1) {
    int t = (tid >= off) ? tmp[tid - off] : 0;
    __syncthreads();
    tmp[tid] += t;
    __syncthreads();
  }
  if (tid < nb) {
    int excl = tmp[tid] - v;
    bucketOffsets[tid] = excl;
    bucketCursor[tid] = excl;
  }
  if (tid == 0) bucketOffsets[nb] = tmp[255];
}

__global__ void bucket_scatter_kernel(const int* __restrict__ src,
                                      const int* __restrict__ dst,
                                      int* __restrict__ bucketCursor,
                                      int2* __restrict__ binEdges,
                                      int nedge, int nb, int tile) {
  __shared__ int hist[256];
  __shared__ int base[256];
  hist[threadIdx.x] = 0;
  __syncthreads();
  int start = blockIdx.x * tile;
  int end = min(start + tile, nedge);
  for (int e = start + threadIdx.x; e < end; e += 256)
    atomicAdd(&hist[dst[e] >> 8], 1);
  __syncthreads();
  if (threadIdx.x < nb) {
    int c = hist[threadIdx.x];
    base[threadIdx.x] = c ? atomicAdd(&bucketCursor[threadIdx.x], c) : 0;
    hist[threadIdx.x] = 0;
  }
  __syncthreads();
  for (int e = start + threadIdx.x; e < end; e += 256) {
    int b = dst[e] >> 8;
    int r = atomicAdd(&hist[b], 1);
    binEdges[base[b] + r] = make_int2(src[e], dst[e]);
  }
}

__global__ void csr_build_kernel(const int2* __restrict__ binEdges,
                                 const int* __restrict__ bucketOffsets,
                                 int2* __restrict__ rowinfo,
                                 int* __restrict__ csr, int n_nodes) {
  __shared__ int hist[256];
  __shared__ int tmp[256];
  int tid = threadIdx.x;
  int b = blockIdx.x;
  int n0 = b << 8;
  int nLoc = min(256, n_nodes - n0);
  int eBase = bucketOffsets[b];
  int cntE = bucketOffsets[b + 1] - eBase;
  hist[tid] = 0;
  __syncthreads();
  for (int i = tid; i < cntE; i += 256)
    atomicAdd(&hist[binEdges[eBase + i].y - n0], 1);
  __syncthreads();
  int v = (tid < nLoc) ? hist[tid] + 1 : 0;  // +1 = self-loop
  tmp[tid] = v;
  __syncthreads();
#pragma unroll
  for (int off = 1; off < 256; off <<= 1) {
    int t = (tid >= off) ? tmp[tid - off] : 0;
    __syncthreads();
    tmp[tid] += t;
    __syncthreads();
  }
  int excl = tmp[tid] - v;
  __syncthreads();
  if (tid < nLoc) {
    int rowStart = eBase + n0 + excl;
    rowinfo[n0 + tid] = make_int2(rowStart, v);
    csr[rowStart] = n0 + tid;  // self edge in slot 0
    hist[tid] = excl + 1;      // local cursor
  }
  __syncthreads();
  for (int i = tid; i < cntE; i += 256) {
    int2 e = binEdges[eBase + i];
    int l = e.y - n0;
    int r = atomicAdd(&hist[l], 1);
    csr[eBase + n0 + r] = e.x;
  }
}

// ========== fused softmax + weighted gather, wave-per-node ==================
// Fast path (deg<=64): no max-subtraction (cancels exactly; e bounded).
// Gather software-pipelined 8-deep: 8 dwordx4 gathers issued back-to-back
// (predicated weight, idx 0 for inactive — wasted gathers measured ~free).
__global__ void aggregate_kernel(const int2* __restrict__ rowinfo,
                                 const int* __restrict__ csr,
                                 const float* __restrict__ as_,
                                 const float* __restrict__ ad_,
                                 const float* __restrict__ h,
                                 const float* __restrict__ bias,
                                 float* __restrict__ hout, int n_nodes) {
  __shared__ int lds_s[4][64];
  __shared__ float lds_w[4][4 * 68];  // stride 68: conflict-free
  int lane = threadIdx.x & 63;
  int wv = threadIdx.x >> 6;
  int node = (blockIdx.x * blockDim.x + threadIdx.x) >> 6;
  if (node >= n_nodes) return;
  node = __builtin_amdgcn_readfirstlane(node);  // force scalar loads below
  int2 ri = rowinfo[node];
  int row = ri.x;
  int deg = ri.y;
  const float4 ad4 = *(const float4*)(ad_ + node * 4);

  if (deg <= 64) {
    bool valid = lane < deg;
    int s = 0;
    float w0 = 0.f, w1 = 0.f, w2 = 0.f, w3 = 0.f;
    if (valid) {
      s = csr[row + lane];
      const float4 a4 = *(const float4*)(as_ + s * 4);
      w0 = __expf(lrelu(a4.x + ad4.x));
      w1 = __expf(lrelu(a4.y + ad4.y));
      w2 = __expf(lrelu(a4.z + ad4.z));
      w3 = __expf(lrelu(a4.w + ad4.w));
    }
    lds_s[wv][lane] = s;
    lds_w[wv][0 * 68 + lane] = w0;
    lds_w[wv][1 * 68 + lane] = w1;
    lds_w[wv][2 * 68 + lane] = w2;
    lds_w[wv][3 * 68 + lane] = w3;
    // lanes re-split 16x4: 16-lane group g handles edge j = it*4+g, 4 ch/lane
    int grp = lane >> 4;
    int chBase = (lane & 15) * 4;
    int headL = (lane & 15) >> 2;
    const int* sp = &lds_s[wv][0];
    const float* wp = &lds_w[wv][headL * 68];
    float ax = 0.f, ay = 0.f, az = 0.f, aw = 0.f, zacc = 0.f;
    int iters = (deg + 3) >> 2;  // 1..16, wave-uniform
    for (int base = 0; base < iters; base += 8) {
      float4 g[8];
      float u[8];
#pragma unroll
      for (int k = 0; k < 8; ++k) {
        int it = base + k;
        int j = (it * 4 + grp) & 63;
        int sj = sp[j];
        u[k] = (it < iters) ? wp[j] : 0.f;
        g[k] = *(const float4*)(h + (size_t)sj * 64 + chBase);
      }
#pragma unroll
      for (int k = 0; k < 8; ++k) {
        ax = fmaf(u[k], g[k].x, ax);
        ay = fmaf(u[k], g[k].y, ay);
        az = fmaf(u[k], g[k].z, az);
        aw = fmaf(u[k], g[k].w, aw);
        zacc += u[k];
      }
    }
    // combine the 4 edge-groups (lanes L, L^16, L^32, L^48)
    ax += __shfl_xor(ax, 16); ax += __shfl_xor(ax, 32);
    ay += __shfl_xor(ay, 16); ay += __shfl_xor(ay, 32);
    az += __shfl_xor(az, 16); az += __shfl_xor(az, 32);
    aw += __shfl_xor(aw, 16); aw += __shfl_xor(aw, 32);
    zacc += __shfl_xor(zacc, 16); zacc += __shfl_xor(zacc, 32);
    if (lane < 16) {
      const float4 b4 = *(const float4*)(bias + chBase);
      float4 o;
      o.x = ax / zacc + b4.x;
      o.y = ay / zacc + b4.y;
      o.z = az / zacc + b4.z;
      o.w = aw / zacc + b4.w;
      *(float4*)(hout + (size_t)node * 64 + chBase) = o;
    }
    return;
  }

  // --- slow path (deg > 64): two-pass with max, scalar gather (rare) ---
  int head = lane >> 4;
  float m0 = -INFINITY, m1 = -INFINITY, m2 = -INFINITY, m3 = -INFINITY;
  for (int base = 0; base < deg; base += 64) {
    int idx = base + lane;
    if (idx < deg) {
      int s = csr[row + idx];
      const float4 a4 = *(const float4*)(as_ + s * 4);
      m0 = fmaxf(m0, lrelu(a4.x + ad4.x));
      m1 = fmaxf(m1, lrelu(a4.y + ad4.y));
      m2 = fmaxf(m2, lrelu(a4.z + ad4.z));
      m3 = fmaxf(m3, lrelu(a4.w + ad4.w));
    }
  }
#pragma unroll
  for (int off = 32; off; off >>= 1) {
    m0 = fmaxf(m0, __shfl_xor(m0, off));
    m1 = fmaxf(m1, __shfl_xor(m1, off));
    m2 = fmaxf(m2, __shfl_xor(m2, off));
    m3 = fmaxf(m3, __shfl_xor(m3, off));
  }
  float z0 = 0.f, z1 = 0.f, z2 = 0.f, z3 = 0.f;
  float acc = 0.f;
  for (int base = 0; base < deg; base += 64) {
    int idx = base + lane;
    int s = 0;
    float w0 = 0.f, w1 = 0.f, w2 = 0.f, w3 = 0.f;
    if (idx < deg) {
      s = csr[row + idx];
      const float4 a4 = *(const float4*)(as_ + s * 4);
      w0 = __expf(lrelu(a4.x + ad4.x) - m0);
      w1 = __expf(lrelu(a4.y + ad4.y) - m1);
      w2 = __expf(lrelu(a4.z + ad4.z) - m2);
      w3 = __expf(lrelu(a4.w + ad4.w) - m3);
    }
    z0 += w0; z1 += w1; z2 += w2; z3 += w3;
    lds_s[wv][lane] = s;
    lds_w[wv][0 * 68 + lane] = w0;
    lds_w[wv][1 * 68 + lane] = w1;
    lds_w[wv][2 * 68 + lane] = w2;
    lds_w[wv][3 * 68 + lane] = w3;
    int cnt = min(64, deg - base);
    for (int j = 0; j < cnt; ++j) {
      int sj = lds_s[wv][j];
      float wj = lds_w[wv][head * 68 + j];
      acc = fmaf(wj, h[(size_t)sj * 64 + lane], acc);
    }
  }
#pragma unroll
  for (int off = 32; off; off >>= 1) {
    z0 += __shfl_xor(z0, off);
    z1 += __shfl_xor(z1, off);
    z2 += __shfl_xor(z2, off);
    z3 += __shfl_xor(z3, off);
  }
  float zsel = head == 0 ? z0 : head == 1 ? z1 : head == 2 ? z2 : z3;
  hout[(size_t)node * 64 + lane] = acc / zsel + bias[lane];
}

// =============================== pooling ====================================

// wave per 16 nodes; batch sorted -> one atomic per segment boundary
__global__ void pool_kernel(const float* __restrict__ h,
                            const int* __restrict__ batch,
                            float* __restrict__ pool,
                            float* __restrict__ cnt, int n_nodes) {
  int lane = threadIdx.x & 63;
  int wave = (blockIdx.x * blockDim.x + threadIdx.x) >> 6;
  int n0 = wave * 16;
  if (n0 >= n_nodes) return;
  int n1 = min(n0 + 16, n_nodes);
  int gcur = batch[n0];
  float acc = 0.f, c_acc = 0.f;
  for (int n = n0; n < n1; ++n) {
    int g = batch[n];
    if (g != gcur) {
      atomicAdd(&pool[gcur * 64 + lane], acc);
      if (lane == 0) atomicAdd(&cnt[gcur], c_acc);
      acc = 0.f; c_acc = 0.f; gcur = g;
    }
    acc += h[(size_t)n * 64 + lane];
    c_acc += 1.f;
  }
  atomicAdd(&pool[gcur * 64 + lane], acc);
  if (lane == 0) atomicAdd(&cnt[gcur], c_acc);
}

__global__ void final_kernel(const float* __restrict__ pool,
                             const float* __restrict__ cnt,
                             const float* __restrict__ Wf,
                             const float* __restrict__ bf,
                             float* __restrict__ out) {
  int g = blockIdx.x;
  int o = threadIdx.x;
  if (o >= 5) return;
  float cg = cnt[g];
  cg = cg > 1.f ? cg : 1.f;
  float acc = bf[o];
  for (int c = 0; c < 64; ++c)
    acc += (pool[g * 64 + c] / cg) * Wf[c * 5 + o];
  out[g * 5 + o] = acc;
}

extern "C" void kernel_launch(void* const* d_in, const int* in_sizes, int n_in,
                              void* d_out, int out_size, void* d_ws, size_t ws_size,
                              hipStream_t stream) {
  const float* x     = (const float*)d_in[0];
  const int*   ei    = (const int*)d_in[1];
  const int*   batch = (const int*)d_in[2];
  const float* W0    = (const float*)d_in[3];
  const float* as0   = (const float*)d_in[4];
  const float* ad0   = (const float*)d_in[5];
  const float* b0    = (const float*)d_in[6];
  const float* Wh    = (const float*)d_in[7];
  const float* ash   = (const float*)d_in[8];
  const float* adh   = (const float*)d_in[9];
  const float* bh    = (const float*)d_in[10];
  const float* Wf    = (const float*)d_in[11];
  const float* bf    = (const float*)d_in[12];
  float* out = (float*)d_out;

  const int N = in_sizes[0];       // 50000
  const int E = in_sizes[1] / 2;   // 800000
  const int* src = ei;
  const int* dst = ei + E;
  const int nE = E + N;
  const int NB = (N + 255) >> 8;   // buckets of 256 nodes (196)

  // workspace layout (pool/cnt/bucketCounts contiguous -> single memset)
  float* ws  = (float*)d_ws;
  float* hA  = ws;                              // N*64
  float* hB  = hA + (size_t)N * 64;             // N*64
  float* asb = hB + (size_t)N * 64;             // N*4
  float* adb = asb + (size_t)N * 4;             // N*4
  int2* rowinfo = (int2*)(adb + (size_t)N * 4); // N int2
  int* csr     = (int*)(rowinfo + N);           // nE
  int2* binEdges = (int2*)(csr + nE);           // E int2
  float* pool  = (float*)(binEdges + E);        // 64*64
  float* cnt   = pool + NGRAPH * 64;            // 64
  int* bucketCounts  = (int*)(cnt + NGRAPH);    // NB+1
  int* bucketOffsets = bucketCounts + NB + 1;   // NB+1
  int* bucketCursor  = bucketOffsets + NB + 1;  // NB

  const int TILE = 2048;
  const int binBlocks = (E + TILE - 1) / TILE;
  const int nodeWaveBlocks = (N + 3) / 4;
  const int poolWaves = (N + 15) / 16;
  const int poolBlocks = (poolWaves + 3) / 4;

  // zero pool + cnt + bucketCounts in one contiguous async memset
  hipMemsetAsync(pool, 0, (size_t)(NGRAPH * 64 + NGRAPH + NB + 1) * sizeof(int), stream);
  // fused layer-0 transform + bucket histogram
  t0_hist_kernel<<<binBlocks + 2048, 256, 0, stream>>>(x, W0, as0, ad0, hA, asb, adb, N,
                                                       dst, bucketCounts, E, NB, TILE, binBlocks);
  bucket_scan_kernel<<<1, 256, 0, stream>>>(bucketCounts, bucketOffsets, bucketCursor, NB);
  bucket_scatter_kernel<<<binBlocks, 256, 0, stream>>>(src, dst, bucketCursor, binEdges, E, NB, TILE);
  csr_build_kernel<<<NB, 256, 0, stream>>>(binEdges, bucketOffsets, rowinfo, csr, N);

  for (int layer = 0; layer < 4; ++layer) {
    if (layer > 0) {
      transform_kernel<<<2048, 256, 0, stream>>>(hB, Wh + (size_t)(layer - 1) * 64 * 64,
                                                 ash + (layer - 1) * 64, adh + (layer - 1) * 64,
                                                 hA, asb, adb, N);
    }
    const float* bias = (layer == 0) ? b0 : (bh + (layer - 1) * 64);
    aggregate_kernel<<<nodeWaveBlocks, 256, 0, stream>>>(rowinfo, csr,
                                                         asb, adb, hA, bias, hB, N);
  }

  pool_kernel<<<poolBlocks, 256, 0, stream>>>(hB, batch, pool, cnt, N);
  final_kernel<<<NGRAPH, 64, 0, stream>>>(pool, cnt, Wf, bf, out);
}